// Round 6
// baseline (456.859 us; speedup 1.0000x reference)
//
#include <hip/hip_runtime.h>

typedef __attribute__((ext_vector_type(8))) short bf16x8;
typedef __attribute__((ext_vector_type(8))) unsigned short u16x8;
typedef __attribute__((ext_vector_type(4))) unsigned short u16x4;
typedef __attribute__((ext_vector_type(4))) float f32x4;
typedef unsigned short u16t;

#define MFMA16(a, b, c) __builtin_amdgcn_mfma_f32_16x16x32_bf16((a), (b), (c), 0, 0, 0)
#define GLDS16(gp, lp)                                                        \
  __builtin_amdgcn_global_load_lds(                                           \
      (__attribute__((address_space(1))) void*)(gp),                          \
      (__attribute__((address_space(3))) void*)(lp), 16, 0, 0)

static constexpr float L2E = 1.44269504f;   // log2(e)
static constexpr float MASKV = -1.0e30f;    // finite mask sentinel (no inf paths)
static constexpr float MASKTH = -5.0e29f;   // "is real score" threshold

__device__ __forceinline__ u16t f2b(float f) {
  unsigned u = __builtin_bit_cast(unsigned, f);
  u = u + 0x7fffu + ((u >> 16) & 1u); // RNE
  return (u16t)(u >> 16);
}

// ---------------------------------------------------------------------------
// fp32 -> bf16 conversion of x and the 4 weight matrices, one fused launch.
// ---------------------------------------------------------------------------
__global__ void cvt5(const float* __restrict__ x, const float* __restrict__ wq,
                     const float* __restrict__ wk, const float* __restrict__ wv,
                     const float* __restrict__ wo, u16t* __restrict__ xb,
                     u16t* __restrict__ wqb, u16t* __restrict__ wkb,
                     u16t* __restrict__ wvb, u16t* __restrict__ wob) {
  const int bid = blockIdx.x;
  const float* src; u16t* dst; int gb;
  if (bid < 4096)      { src = x;  dst = xb;  gb = bid; }
  else if (bid < 4608) { src = wq; dst = wqb; gb = bid - 4096; }
  else if (bid < 5120) { src = wk; dst = wkb; gb = bid - 4608; }
  else if (bid < 5632) { src = wv; dst = wvb; gb = bid - 5120; }
  else                 { src = wo; dst = wob; gb = bid - 5632; }
  const size_t i = (size_t)gb * 256 + threadIdx.x; // 8-elem group index
  const float4 a = ((const float4*)src)[2 * i];
  const float4 b = ((const float4*)src)[2 * i + 1];
  u16x8 r;
  r[0] = f2b(a.x); r[1] = f2b(a.y); r[2] = f2b(a.z); r[3] = f2b(a.w);
  r[4] = f2b(b.x); r[5] = f2b(b.y); r[6] = f2b(b.z); r[7] = f2b(b.w);
  *(u16x8*)&dst[8 * i] = r;
}

// ---------------------------------------------------------------------------
// QKV GEMM. Q,K written [B,H,S,HD]; V written TRANSPOSED [B,H,HD,S] so the
// attention k-loop can read V^T fragments straight from global (no LDS
// transpose, no barriers).
// ---------------------------------------------------------------------------
__global__ void gemm_qkv(const u16t* __restrict__ X,
                         const u16t* __restrict__ Wq, const u16t* __restrict__ Wk,
                         const u16t* __restrict__ Wv,
                         const float* __restrict__ bq, const float* __restrict__ bk,
                         const float* __restrict__ bv,
                         u16t* __restrict__ Qo, u16t* __restrict__ Ko,
                         u16t* __restrict__ Vo) {
  __shared__ __align__(16) u16t As[128 * 32];
  __shared__ __align__(16) u16t Bs[128 * 32];
  const int t = threadIdx.x, lane = t & 63, w = t >> 6;
  const int wr = w >> 1, wc = w & 1, m = lane & 15, quad = lane >> 4;
  const int rowBase = blockIdx.y * 128, colBase = blockIdx.x * 128;
  const int z = blockIdx.z;
  const u16t* W = (z == 0) ? Wq : ((z == 1) ? Wk : Wv);
  const float* bias = (z == 0) ? bq : ((z == 1) ? bk : bv);
  u16t* Out = (z == 0) ? Qo : ((z == 1) ? Ko : Vo);

  f32x4 acc[4][4];
#pragma unroll
  for (int i = 0; i < 4; i++)
#pragma unroll
    for (int j = 0; j < 4; j++) acc[i][j] = (f32x4){0.f, 0.f, 0.f, 0.f};

  const int lr = lane >> 2, lc = (lane & 3) * 8;
  for (int kt = 0; kt < 32; ++kt) {
#pragma unroll
    for (int i = 0; i < 2; ++i) {
      const int r0 = i * 64 + w * 16; // wave-uniform LDS region base
      GLDS16(&X[(size_t)(rowBase + r0 + lr) * 1024 + kt * 32 + lc], &As[r0 * 32]);
      GLDS16(&W[(size_t)(colBase + r0 + lr) * 1024 + kt * 32 + lc], &Bs[r0 * 32]);
    }
    __syncthreads();
    bf16x8 af[4], bfr[4];
#pragma unroll
    for (int i = 0; i < 4; i++)
      af[i] = *(const bf16x8*)&As[(wr * 64 + i * 16 + m) * 32 + quad * 8];
#pragma unroll
    for (int j = 0; j < 4; j++)
      bfr[j] = *(const bf16x8*)&Bs[(wc * 64 + j * 16 + m) * 32 + quad * 8];
#pragma unroll
    for (int i = 0; i < 4; i++)
#pragma unroll
      for (int j = 0; j < 4; j++) acc[i][j] = MFMA16(af[i], bfr[j], acc[i][j]);
    __syncthreads();
  }

#pragma unroll
  for (int j = 0; j < 4; j++) {
    const int col = colBase + wc * 64 + j * 16 + m;
    const float bv_ = bias[col];
    const int h = col >> 6, hd = col & 63;
#pragma unroll
    for (int i = 0; i < 4; i++) {
#pragma unroll
      for (int r = 0; r < 4; r++) {
        const int row = rowBase + wr * 64 + i * 16 + quad * 4 + r;
        const int b_ = row >> 10, s_ = row & 1023;
        const size_t oi =
            (z == 2) ? ((((size_t)b_ * 16 + h) * 64 + hd) * 1024 + s_)   // V^T
                     : ((((size_t)b_ * 16 + h) * 1024 + s_) * 64 + hd);  // Q,K
        Out[oi] = f2b(acc[i][j][r] + bv_);
      }
    }
  }
}

__global__ void gemm_o(const u16t* __restrict__ A, const u16t* __restrict__ W,
                       const float* __restrict__ bias, float* __restrict__ Out) {
  __shared__ __align__(16) u16t As[128 * 32];
  __shared__ __align__(16) u16t Bs[128 * 32];
  const int t = threadIdx.x, lane = t & 63, w = t >> 6;
  const int wr = w >> 1, wc = w & 1, m = lane & 15, quad = lane >> 4;
  const int rowBase = blockIdx.y * 128, colBase = blockIdx.x * 128;

  f32x4 acc[4][4];
#pragma unroll
  for (int i = 0; i < 4; i++)
#pragma unroll
    for (int j = 0; j < 4; j++) acc[i][j] = (f32x4){0.f, 0.f, 0.f, 0.f};

  const int lr = lane >> 2, lc = (lane & 3) * 8;
  for (int kt = 0; kt < 32; ++kt) {
#pragma unroll
    for (int i = 0; i < 2; ++i) {
      const int r0 = i * 64 + w * 16;
      GLDS16(&A[(size_t)(rowBase + r0 + lr) * 1024 + kt * 32 + lc], &As[r0 * 32]);
      GLDS16(&W[(size_t)(colBase + r0 + lr) * 1024 + kt * 32 + lc], &Bs[r0 * 32]);
    }
    __syncthreads();
    bf16x8 af[4], bfr[4];
#pragma unroll
    for (int i = 0; i < 4; i++)
      af[i] = *(const bf16x8*)&As[(wr * 64 + i * 16 + m) * 32 + quad * 8];
#pragma unroll
    for (int j = 0; j < 4; j++)
      bfr[j] = *(const bf16x8*)&Bs[(wc * 64 + j * 16 + m) * 32 + quad * 8];
#pragma unroll
    for (int i = 0; i < 4; i++)
#pragma unroll
      for (int j = 0; j < 4; j++) acc[i][j] = MFMA16(af[i], bfr[j], acc[i][j]);
    __syncthreads();
  }

#pragma unroll
  for (int j = 0; j < 4; j++) {
    const int col = colBase + wc * 64 + j * 16 + m;
    const float bv_ = bias[col];
#pragma unroll
    for (int i = 0; i < 4; i++) {
#pragma unroll
      for (int r = 0; r < 4; r++) {
        const int row = rowBase + wr * 64 + i * 16 + quad * 4 + r;
        Out[(size_t)row * 1024 + col] = acc[i][j][r] + bv_;
      }
    }
  }
}

// ---------------------------------------------------------------------------
// Flash attention v2: grid (S/64, H, B), 256 thr, 4 independent waves.
// S^T = K·Q^T (row=key, col=q): softmax per q = per LANE -> in-lane reduce +
// 2 shuffles. O^T = V^T·P^T with V^T frags from global, P^T per-wave LDS
// round-trip (4x ds_write_b64 + 2x ds_read_b128). NO barriers in the k-loop.
// PSTR=72 (>=64 keys/row!  row=144 B: b128-aligned, de-pow2 bank stride).
// ---------------------------------------------------------------------------
__global__ void attn(const u16t* __restrict__ Q, const u16t* __restrict__ K,
                     const u16t* __restrict__ VT, const int* __restrict__ ids,
                     u16t* __restrict__ Oo) {
  constexpr int PSTR = 72; // elems; MUST be >= 64 (keys per row)
  __shared__ __align__(16) float maskS[1024];
  __shared__ __align__(16) u16t Ps[4][16 * PSTR];
  const int t = threadIdx.x, lane = t & 63, w = t >> 6;
  const int m = lane & 15, quad = lane >> 4;
  const int qt = blockIdx.x, h = blockIdx.y, b = blockIdx.z;
  const size_t hoff = ((size_t)b * 16 + h) * 1024 * 64;
  const int qbase = qt * 64 + w * 16;
  const int q = qbase + m; // this lane's query row

  // pad-mask -> LDS (additive: 0 or -1e30), once per block
  {
    const int4 iv = *(const int4*)&ids[b * 1024 + t * 4];
    float4 mv;
    mv.x = (iv.x == 1) ? MASKV : 0.f;
    mv.y = (iv.y == 1) ? MASKV : 0.f;
    mv.z = (iv.z == 1) ? MASKV : 0.f;
    mv.w = (iv.w == 1) ? MASKV : 0.f;
    *(float4*)&maskS[t * 4] = mv;
  }
  __syncthreads();

  // Q fragment (B-operand): lane m holds Q[q][quad*8..+7]
  const bf16x8 qf0 = *(const bf16x8*)&Q[hoff + (size_t)q * 64 + quad * 8];
  const bf16x8 qf1 = *(const bf16x8*)&Q[hoff + (size_t)q * 64 + 32 + quad * 8];

  float mi = MASKV, li = 0.f;
  f32x4 o[4]; // O^T C-layout: o[ot][r] = O[q][ot*16+quad*4+r]
#pragma unroll
  for (int ot = 0; ot < 4; ot++) o[ot] = (f32x4){0.f, 0.f, 0.f, 0.f};

  for (int kt = 0; kt <= qt; ++kt) {
    const int kb = kt * 64;
    // ---- scores S^T (4 tiles of 16 keys) ----
    f32x4 sc[4];
    float rmax = MASKV;
#pragma unroll
    for (int nt = 0; nt < 4; nt++) {
      const bool active = (kb + nt * 16) <= (qbase + 15); // wave-uniform
      if (active) {
        const int key = kb + nt * 16 + m; // A-frag row
        const bf16x8 k0 = *(const bf16x8*)&K[hoff + (size_t)key * 64 + quad * 8];
        const bf16x8 k1 = *(const bf16x8*)&K[hoff + (size_t)key * 64 + 32 + quad * 8];
        f32x4 c = (f32x4){0.f, 0.f, 0.f, 0.f};
        c = MFMA16(k0, qf0, c);
        c = MFMA16(k1, qf1, c);
        const float4 madd = *(const float4*)&maskS[kb + nt * 16 + quad * 4];
        const int kq = q - kb - nt * 16 - quad * 4; // causal: r <= kq
        const float ma[4] = {madd.x, madd.y, madd.z, madd.w};
#pragma unroll
        for (int r = 0; r < 4; r++) {
          float s = c[r] * 0.125f + ma[r];
          s = (r <= kq) ? s : MASKV;
          sc[nt][r] = s;
          rmax = fmaxf(rmax, s);
        }
      } else {
#pragma unroll
        for (int r = 0; r < 4; r++) sc[nt][r] = MASKV;
      }
    }
    // full 64-key max for this lane's q: combine quads
    rmax = fmaxf(rmax, __shfl_xor(rmax, 16));
    rmax = fmaxf(rmax, __shfl_xor(rmax, 32));
    const float mn = fmaxf(mi, rmax);
    const float alpha = exp2f((mi - mn) * L2E);
    mi = mn;

    // ---- P^T = exp(S^T - m) -> bf16 -> per-wave LDS [q][key] ----
    float rsum = 0.f;
#pragma unroll
    for (int nt = 0; nt < 4; nt++) {
      u16x4 pw;
#pragma unroll
      for (int r = 0; r < 4; r++) {
        const float p =
            (sc[nt][r] > MASKTH) ? exp2f((sc[nt][r] - mi) * L2E) : 0.f;
        rsum += p;
        pw[r] = f2b(p);
      }
      *(u16x4*)&Ps[w][m * PSTR + nt * 16 + quad * 4] = pw;
    }
    rsum += __shfl_xor(rsum, 16);
    rsum += __shfl_xor(rsum, 32);
    li = li * alpha + rsum;

    // ---- O^T = alpha*O^T + V^T @ P^T ----
#pragma unroll
    for (int ot = 0; ot < 4; ot++)
#pragma unroll
      for (int r = 0; r < 4; r++) o[ot][r] *= alpha;

    const bf16x8 p0 = *(const bf16x8*)&Ps[w][m * PSTR + quad * 8];      // keys 0..31
    const bf16x8 p1 = *(const bf16x8*)&Ps[w][m * PSTR + 32 + quad * 8]; // keys 32..63
#pragma unroll
    for (int ot = 0; ot < 4; ot++) {
      const int hd = ot * 16 + m; // A-frag row = hd
      const bf16x8 v0 = *(const bf16x8*)&VT[hoff + (size_t)hd * 1024 + kb + quad * 8];
      const bf16x8 v1 = *(const bf16x8*)&VT[hoff + (size_t)hd * 1024 + kb + 32 + quad * 8];
      o[ot] = MFMA16(v0, p0, o[ot]);
      o[ot] = MFMA16(v1, p1, o[ot]);
    }
  }

  // epilogue: lane owns q-row; cols h*64 + ot*16 + quad*4 + r (4 contiguous)
  const float inv = li > 1e-30f ? 1.f / li : 0.f;
#pragma unroll
  for (int ot = 0; ot < 4; ot++) {
    u16x4 ow;
#pragma unroll
    for (int r = 0; r < 4; r++) ow[r] = f2b(o[ot][r] * inv);
    *(u16x4*)&Oo[((size_t)(b * 1024 + q)) * 1024 + h * 64 + ot * 16 + quad * 4] = ow;
  }
}

// ---------------------------------------------------------------------------
extern "C" void kernel_launch(void* const* d_in, const int* in_sizes, int n_in,
                              void* d_out, int out_size, void* d_ws, size_t ws_size,
                              hipStream_t stream) {
  const float* x  = (const float*)d_in[0];
  const int*   ids = (const int*)d_in[1];
  const float* Wq = (const float*)d_in[2];
  const float* bq = (const float*)d_in[3];
  const float* Wk = (const float*)d_in[4];
  const float* bk = (const float*)d_in[5];
  const float* Wv = (const float*)d_in[6];
  const float* bv = (const float*)d_in[7];
  const float* Wo = (const float*)d_in[8];
  const float* bo = (const float*)d_in[9];
  float* out = (float*)d_out;

  // ws layout (bf16 elems): XB 8.4M | WqB,WkB,WvB,WoB 1M each | Q,K,V^T 8.4M
  u16t* XB  = (u16t*)d_ws;
  u16t* WqB = XB  + 8388608;
  u16t* WkB = WqB + 1048576;
  u16t* WvB = WkB + 1048576;
  u16t* WoB = WvB + 1048576;
  u16t* Qw  = WoB + 1048576;
  u16t* Kw  = Qw  + 8388608;
  u16t* Vw  = Kw  + 8388608; // holds V^T [B,H,HD,S]
  u16t* AO  = XB; // reuse after gemm_qkv consumed XB

  cvt5<<<6144, 256, 0, stream>>>(x, Wq, Wk, Wv, Wo, XB, WqB, WkB, WvB, WoB);
  gemm_qkv<<<dim3(8, 64, 3), 256, 0, stream>>>(XB, WqB, WkB, WvB, bq, bk, bv,
                                               Qw, Kw, Vw);
  attn<<<dim3(16, 16, 8), 256, 0, stream>>>(Qw, Kw, Vw, ids, AO);
  gemm_o<<<dim3(8, 64, 1), 256, 0, stream>>>(AO, WoB, bo, out);
}

// Round 8
// 409.198 us; speedup vs baseline: 1.1165x; 1.1165x over previous
//
#include <hip/hip_runtime.h>

typedef __attribute__((ext_vector_type(8))) short bf16x8;
typedef __attribute__((ext_vector_type(8))) unsigned short u16x8;
typedef __attribute__((ext_vector_type(4))) unsigned short u16x4;
typedef __attribute__((ext_vector_type(4))) float f32x4;
typedef unsigned short u16t;

#define MFMA16(a, b, c) __builtin_amdgcn_mfma_f32_16x16x32_bf16((a), (b), (c), 0, 0, 0)
#define GLDS16(gp, lp)                                                        \
  __builtin_amdgcn_global_load_lds(                                           \
      (__attribute__((address_space(1))) void*)(gp),                          \
      (__attribute__((address_space(3))) void*)(lp), 16, 0, 0)

static constexpr float L2E = 1.44269504f;   // log2(e)
static constexpr float MASKV = -1.0e30f;    // finite mask sentinel (no inf paths)
static constexpr float MASKTH = -5.0e29f;   // "is real score" threshold

__device__ __forceinline__ u16t f2b(float f) {
  unsigned u = __builtin_bit_cast(unsigned, f);
  u = u + 0x7fffu + ((u >> 16) & 1u); // RNE
  return (u16t)(u >> 16);
}

// ---------------------------------------------------------------------------
// fp32 -> bf16 conversion of x and the 4 weight matrices, one fused launch.
// ---------------------------------------------------------------------------
__global__ void cvt5(const float* __restrict__ x, const float* __restrict__ wq,
                     const float* __restrict__ wk, const float* __restrict__ wv,
                     const float* __restrict__ wo, u16t* __restrict__ xb,
                     u16t* __restrict__ wqb, u16t* __restrict__ wkb,
                     u16t* __restrict__ wvb, u16t* __restrict__ wob) {
  const int bid = blockIdx.x;
  const float* src; u16t* dst; int gb;
  if (bid < 4096)      { src = x;  dst = xb;  gb = bid; }
  else if (bid < 4608) { src = wq; dst = wqb; gb = bid - 4096; }
  else if (bid < 5120) { src = wk; dst = wkb; gb = bid - 4608; }
  else if (bid < 5632) { src = wv; dst = wvb; gb = bid - 5120; }
  else                 { src = wo; dst = wob; gb = bid - 5632; }
  const size_t i = (size_t)gb * 256 + threadIdx.x; // 8-elem group index
  const float4 a = ((const float4*)src)[2 * i];
  const float4 b = ((const float4*)src)[2 * i + 1];
  u16x8 r;
  r[0] = f2b(a.x); r[1] = f2b(a.y); r[2] = f2b(a.z); r[3] = f2b(a.w);
  r[4] = f2b(b.x); r[5] = f2b(b.y); r[6] = f2b(b.z); r[7] = f2b(b.w);
  *(u16x8*)&dst[8 * i] = r;
}

// ---------------------------------------------------------------------------
// QKV GEMM. Q,K written [B,H,S,HD]; V written TRANSPOSED [B,H,HD,S].
// ---------------------------------------------------------------------------
__global__ void gemm_qkv(const u16t* __restrict__ X,
                         const u16t* __restrict__ Wq, const u16t* __restrict__ Wk,
                         const u16t* __restrict__ Wv,
                         const float* __restrict__ bq, const float* __restrict__ bk,
                         const float* __restrict__ bv,
                         u16t* __restrict__ Qo, u16t* __restrict__ Ko,
                         u16t* __restrict__ Vo) {
  __shared__ __align__(16) u16t As[128 * 32];
  __shared__ __align__(16) u16t Bs[128 * 32];
  const int t = threadIdx.x, lane = t & 63, w = t >> 6;
  const int wr = w >> 1, wc = w & 1, m = lane & 15, quad = lane >> 4;
  const int rowBase = blockIdx.y * 128, colBase = blockIdx.x * 128;
  const int z = blockIdx.z;
  const u16t* W = (z == 0) ? Wq : ((z == 1) ? Wk : Wv);
  const float* bias = (z == 0) ? bq : ((z == 1) ? bk : bv);
  u16t* Out = (z == 0) ? Qo : ((z == 1) ? Ko : Vo);

  f32x4 acc[4][4];
#pragma unroll
  for (int i = 0; i < 4; i++)
#pragma unroll
    for (int j = 0; j < 4; j++) acc[i][j] = (f32x4){0.f, 0.f, 0.f, 0.f};

  const int lr = lane >> 2, lc = (lane & 3) * 8;
  for (int kt = 0; kt < 32; ++kt) {
#pragma unroll
    for (int i = 0; i < 2; ++i) {
      const int r0 = i * 64 + w * 16; // wave-uniform LDS region base
      GLDS16(&X[(size_t)(rowBase + r0 + lr) * 1024 + kt * 32 + lc], &As[r0 * 32]);
      GLDS16(&W[(size_t)(colBase + r0 + lr) * 1024 + kt * 32 + lc], &Bs[r0 * 32]);
    }
    __syncthreads();
    bf16x8 af[4], bfr[4];
#pragma unroll
    for (int i = 0; i < 4; i++)
      af[i] = *(const bf16x8*)&As[(wr * 64 + i * 16 + m) * 32 + quad * 8];
#pragma unroll
    for (int j = 0; j < 4; j++)
      bfr[j] = *(const bf16x8*)&Bs[(wc * 64 + j * 16 + m) * 32 + quad * 8];
#pragma unroll
    for (int i = 0; i < 4; i++)
#pragma unroll
      for (int j = 0; j < 4; j++) acc[i][j] = MFMA16(af[i], bfr[j], acc[i][j]);
    __syncthreads();
  }

#pragma unroll
  for (int j = 0; j < 4; j++) {
    const int col = colBase + wc * 64 + j * 16 + m;
    const float bv_ = bias[col];
    const int h = col >> 6, hd = col & 63;
#pragma unroll
    for (int i = 0; i < 4; i++) {
#pragma unroll
      for (int r = 0; r < 4; r++) {
        const int row = rowBase + wr * 64 + i * 16 + quad * 4 + r;
        const int b_ = row >> 10, s_ = row & 1023;
        const size_t oi =
            (z == 2) ? ((((size_t)b_ * 16 + h) * 64 + hd) * 1024 + s_)   // V^T
                     : ((((size_t)b_ * 16 + h) * 1024 + s_) * 64 + hd);  // Q,K
        Out[oi] = f2b(acc[i][j][r] + bv_);
      }
    }
  }
}

__global__ void gemm_o(const u16t* __restrict__ A, const u16t* __restrict__ W,
                       const float* __restrict__ bias, float* __restrict__ Out) {
  __shared__ __align__(16) u16t As[128 * 32];
  __shared__ __align__(16) u16t Bs[128 * 32];
  const int t = threadIdx.x, lane = t & 63, w = t >> 6;
  const int wr = w >> 1, wc = w & 1, m = lane & 15, quad = lane >> 4;
  const int rowBase = blockIdx.y * 128, colBase = blockIdx.x * 128;

  f32x4 acc[4][4];
#pragma unroll
  for (int i = 0; i < 4; i++)
#pragma unroll
    for (int j = 0; j < 4; j++) acc[i][j] = (f32x4){0.f, 0.f, 0.f, 0.f};

  const int lr = lane >> 2, lc = (lane & 3) * 8;
  for (int kt = 0; kt < 32; ++kt) {
#pragma unroll
    for (int i = 0; i < 2; ++i) {
      const int r0 = i * 64 + w * 16;
      GLDS16(&A[(size_t)(rowBase + r0 + lr) * 1024 + kt * 32 + lc], &As[r0 * 32]);
      GLDS16(&W[(size_t)(colBase + r0 + lr) * 1024 + kt * 32 + lc], &Bs[r0 * 32]);
    }
    __syncthreads();
    bf16x8 af[4], bfr[4];
#pragma unroll
    for (int i = 0; i < 4; i++)
      af[i] = *(const bf16x8*)&As[(wr * 64 + i * 16 + m) * 32 + quad * 8];
#pragma unroll
    for (int j = 0; j < 4; j++)
      bfr[j] = *(const bf16x8*)&Bs[(wc * 64 + j * 16 + m) * 32 + quad * 8];
#pragma unroll
    for (int i = 0; i < 4; i++)
#pragma unroll
      for (int j = 0; j < 4; j++) acc[i][j] = MFMA16(af[i], bfr[j], acc[i][j]);
    __syncthreads();
  }

#pragma unroll
  for (int j = 0; j < 4; j++) {
    const int col = colBase + wc * 64 + j * 16 + m;
    const float bv_ = bias[col];
#pragma unroll
    for (int i = 0; i < 4; i++) {
#pragma unroll
      for (int r = 0; r < 4; r++) {
        const int row = rowBase + wr * 64 + i * 16 + quad * 4 + r;
        Out[(size_t)row * 1024 + col] = acc[i][j][r] + bv_;
      }
    }
  }
}

// ---------------------------------------------------------------------------
// Flash attention v3: paired q-tiles for load balance + shared K/V + dual
// dependency chains. Grid (16 h, 8 p, 8 b) = 1024 blocks = 4/CU; flat%8 ==
// h%8 co-locates all blocks of one (b,h) on one XCD (L2 locality). Block
// handles qtA=p (qtA+1 k-tiles) and qtB=15-p (16-p k-tiles): joint phase
// shares K/V fragment loads between both tiles; 17 MFMA-tiles/block uniform.
// No barriers in the k-loop.
// ---------------------------------------------------------------------------
__global__ void attn(const u16t* __restrict__ Q, const u16t* __restrict__ K,
                     const u16t* __restrict__ VT, const int* __restrict__ ids,
                     u16t* __restrict__ Oo) {
  constexpr int PSTR = 72; // >= 64 keys/row; 144 B: b128-aligned, de-pow2 banks
  __shared__ __align__(16) float maskS[1024];
  __shared__ __align__(16) u16t Ps[4][2][16 * PSTR];
  const int t = threadIdx.x, lane = t & 63, w = t >> 6;
  const int m = lane & 15, quad = lane >> 4;
  const int h = blockIdx.x, p = blockIdx.y, b = blockIdx.z;
  const int qtA = p, qtB = 15 - p;
  const size_t hoff = ((size_t)b * 16 + h) * 1024 * 64;
  const int qbaseA = qtA * 64 + w * 16, qbaseB = qtB * 64 + w * 16;
  const int qA = qbaseA + m, qB = qbaseB + m;

  // pad-mask -> LDS (additive: 0 or -1e30), once per block
  {
    const int4 iv = *(const int4*)&ids[b * 1024 + t * 4];
    float4 mv;
    mv.x = (iv.x == 1) ? MASKV : 0.f;
    mv.y = (iv.y == 1) ? MASKV : 0.f;
    mv.z = (iv.z == 1) ? MASKV : 0.f;
    mv.w = (iv.w == 1) ? MASKV : 0.f;
    *(float4*)&maskS[t * 4] = mv;
  }
  __syncthreads();

  // Q fragments (B-operand): lane m holds Q[q][quad*8..+7]
  const bf16x8 qfA0 = *(const bf16x8*)&Q[hoff + (size_t)qA * 64 + quad * 8];
  const bf16x8 qfA1 = *(const bf16x8*)&Q[hoff + (size_t)qA * 64 + 32 + quad * 8];
  const bf16x8 qfB0 = *(const bf16x8*)&Q[hoff + (size_t)qB * 64 + quad * 8];
  const bf16x8 qfB1 = *(const bf16x8*)&Q[hoff + (size_t)qB * 64 + 32 + quad * 8];

  float miA = MASKV, liA = 0.f, miB = MASKV, liB = 0.f;
  f32x4 oA[4], oB[4];
#pragma unroll
  for (int ot = 0; ot < 4; ot++) {
    oA[ot] = (f32x4){0.f, 0.f, 0.f, 0.f};
    oB[ot] = (f32x4){0.f, 0.f, 0.f, 0.f};
  }

  for (int kt = 0; kt <= qtB; ++kt) {
    const int kb = kt * 64;
    const bool joint = (kt <= qtA);

    // ---- scores for both tiles, sharing K fragments ----
    f32x4 scA[4], scB[4];
    float rmaxA = MASKV, rmaxB = MASKV;
#pragma unroll
    for (int nt = 0; nt < 4; nt++) {
      const int kt16 = kb + nt * 16;
      const bool actB = kt16 <= (qbaseB + 15);           // wave-uniform
      const bool actA = joint && (kt16 <= (qbaseA + 15)); // wave-uniform
#pragma unroll
      for (int r = 0; r < 4; r++) { scA[nt][r] = MASKV; scB[nt][r] = MASKV; }
      if (actB || actA) {
        const int key = kt16 + m; // A-frag row
        const bf16x8 k0 = *(const bf16x8*)&K[hoff + (size_t)key * 64 + quad * 8];
        const bf16x8 k1 = *(const bf16x8*)&K[hoff + (size_t)key * 64 + 32 + quad * 8];
        const float4 madd = *(const float4*)&maskS[kt16 + quad * 4];
        const float ma[4] = {madd.x, madd.y, madd.z, madd.w};
        if (actB) {
          f32x4 c = (f32x4){0.f, 0.f, 0.f, 0.f};
          c = MFMA16(k0, qfB0, c);
          c = MFMA16(k1, qfB1, c);
          const int kq = qB - kt16 - quad * 4; // causal: r <= kq
#pragma unroll
          for (int r = 0; r < 4; r++) {
            float s = c[r] * 0.125f + ma[r];
            s = (r <= kq) ? s : MASKV;
            scB[nt][r] = s;
            rmaxB = fmaxf(rmaxB, s);
          }
        }
        if (actA) {
          f32x4 c = (f32x4){0.f, 0.f, 0.f, 0.f};
          c = MFMA16(k0, qfA0, c);
          c = MFMA16(k1, qfA1, c);
          const int kq = qA - kt16 - quad * 4;
#pragma unroll
          for (int r = 0; r < 4; r++) {
            float s = c[r] * 0.125f + ma[r];
            s = (r <= kq) ? s : MASKV;
            scA[nt][r] = s;
            rmaxA = fmaxf(rmaxA, s);
          }
        }
      }
    }

    // ---- V fragments (shared by both PV phases), issued before softmax ----
    bf16x8 vf[4][2];
#pragma unroll
    for (int ot = 0; ot < 4; ot++) {
      const int hd = ot * 16 + m;
      vf[ot][0] = *(const bf16x8*)&VT[hoff + (size_t)hd * 1024 + kb + quad * 8];
      vf[ot][1] = *(const bf16x8*)&VT[hoff + (size_t)hd * 1024 + kb + 32 + quad * 8];
    }

    // ---- softmax B ----
    rmaxB = fmaxf(rmaxB, __shfl_xor(rmaxB, 16));
    rmaxB = fmaxf(rmaxB, __shfl_xor(rmaxB, 32));
    const float mnB = fmaxf(miB, rmaxB);
    const float alphaB = exp2f((miB - mnB) * L2E);
    miB = mnB;
    float rsumB = 0.f;
#pragma unroll
    for (int nt = 0; nt < 4; nt++) {
      u16x4 pw;
#pragma unroll
      for (int r = 0; r < 4; r++) {
        const float pv = (scB[nt][r] > MASKTH) ? exp2f((scB[nt][r] - miB) * L2E) : 0.f;
        rsumB += pv;
        pw[r] = f2b(pv);
      }
      *(u16x4*)&Ps[w][1][m * PSTR + nt * 16 + quad * 4] = pw;
    }
    rsumB += __shfl_xor(rsumB, 16);
    rsumB += __shfl_xor(rsumB, 32);
    liB = liB * alphaB + rsumB;

    // ---- softmax A (joint phase only) ----
    float alphaA = 1.f;
    if (joint) {
      rmaxA = fmaxf(rmaxA, __shfl_xor(rmaxA, 16));
      rmaxA = fmaxf(rmaxA, __shfl_xor(rmaxA, 32));
      const float mnA = fmaxf(miA, rmaxA);
      alphaA = exp2f((miA - mnA) * L2E);
      miA = mnA;
      float rsumA = 0.f;
#pragma unroll
      for (int nt = 0; nt < 4; nt++) {
        u16x4 pw;
#pragma unroll
        for (int r = 0; r < 4; r++) {
          const float pv = (scA[nt][r] > MASKTH) ? exp2f((scA[nt][r] - miA) * L2E) : 0.f;
          rsumA += pv;
          pw[r] = f2b(pv);
        }
        *(u16x4*)&Ps[w][0][m * PSTR + nt * 16 + quad * 4] = pw;
      }
      rsumA += __shfl_xor(rsumA, 16);
      rsumA += __shfl_xor(rsumA, 32);
      liA = liA * alphaA + rsumA;
    }

    // ---- PV for B ----
#pragma unroll
    for (int ot = 0; ot < 4; ot++)
#pragma unroll
      for (int r = 0; r < 4; r++) oB[ot][r] *= alphaB;
    {
      const bf16x8 p0 = *(const bf16x8*)&Ps[w][1][m * PSTR + quad * 8];
      const bf16x8 p1 = *(const bf16x8*)&Ps[w][1][m * PSTR + 32 + quad * 8];
#pragma unroll
      for (int ot = 0; ot < 4; ot++) {
        oB[ot] = MFMA16(vf[ot][0], p0, oB[ot]);
        oB[ot] = MFMA16(vf[ot][1], p1, oB[ot]);
      }
    }
    // ---- PV for A (joint phase only) ----
    if (joint) {
#pragma unroll
      for (int ot = 0; ot < 4; ot++)
#pragma unroll
        for (int r = 0; r < 4; r++) oA[ot][r] *= alphaA;
      const bf16x8 p0 = *(const bf16x8*)&Ps[w][0][m * PSTR + quad * 8];
      const bf16x8 p1 = *(const bf16x8*)&Ps[w][0][m * PSTR + 32 + quad * 8];
#pragma unroll
      for (int ot = 0; ot < 4; ot++) {
        oA[ot] = MFMA16(vf[ot][0], p0, oA[ot]);
        oA[ot] = MFMA16(vf[ot][1], p1, oA[ot]);
      }
    }
  }

  // epilogue: lane owns q-row; cols h*64 + ot*16 + quad*4 + r (4 contiguous)
  const float invA = liA > 1e-30f ? 1.f / liA : 0.f;
  const float invB = liB > 1e-30f ? 1.f / liB : 0.f;
#pragma unroll
  for (int ot = 0; ot < 4; ot++) {
    u16x4 owA, owB;
#pragma unroll
    for (int r = 0; r < 4; r++) {
      owA[r] = f2b(oA[ot][r] * invA);
      owB[r] = f2b(oB[ot][r] * invB);
    }
    const int colb = h * 64 + ot * 16 + quad * 4;
    *(u16x4*)&Oo[((size_t)(b * 1024 + qA)) * 1024 + colb] = owA;
    *(u16x4*)&Oo[((size_t)(b * 1024 + qB)) * 1024 + colb] = owB;
  }
}

// ---------------------------------------------------------------------------
extern "C" void kernel_launch(void* const* d_in, const int* in_sizes, int n_in,
                              void* d_out, int out_size, void* d_ws, size_t ws_size,
                              hipStream_t stream) {
  const float* x  = (const float*)d_in[0];
  const int*   ids = (const int*)d_in[1];
  const float* Wq = (const float*)d_in[2];
  const float* bq = (const float*)d_in[3];
  const float* Wk = (const float*)d_in[4];
  const float* bk = (const float*)d_in[5];
  const float* Wv = (const float*)d_in[6];
  const float* bv = (const float*)d_in[7];
  const float* Wo = (const float*)d_in[8];
  const float* bo = (const float*)d_in[9];
  float* out = (float*)d_out;

  // ws layout (bf16 elems): XB 8.4M | WqB,WkB,WvB,WoB 1M each | Q,K,V^T 8.4M
  u16t* XB  = (u16t*)d_ws;
  u16t* WqB = XB  + 8388608;
  u16t* WkB = WqB + 1048576;
  u16t* WvB = WkB + 1048576;
  u16t* WoB = WvB + 1048576;
  u16t* Qw  = WoB + 1048576;
  u16t* Kw  = Qw  + 8388608;
  u16t* Vw  = Kw  + 8388608; // holds V^T [B,H,HD,S]
  u16t* AO  = XB; // reuse after gemm_qkv consumed XB

  cvt5<<<6144, 256, 0, stream>>>(x, Wq, Wk, Wv, Wo, XB, WqB, WkB, WvB, WoB);
  gemm_qkv<<<dim3(8, 64, 3), 256, 0, stream>>>(XB, WqB, WkB, WvB, bq, bk, bv,
                                               Qw, Kw, Vw);
  attn<<<dim3(16, 8, 8), 256, 0, stream>>>(Qw, Kw, Vw, ids, AO);
  gemm_o<<<dim3(8, 64, 1), 256, 0, stream>>>(AO, WoB, bo, out);
}

// Round 9
// 392.701 us; speedup vs baseline: 1.1634x; 1.0420x over previous
//
#include <hip/hip_runtime.h>

typedef __attribute__((ext_vector_type(8))) short bf16x8;
typedef __attribute__((ext_vector_type(8))) unsigned short u16x8;
typedef __attribute__((ext_vector_type(4))) unsigned short u16x4;
typedef __attribute__((ext_vector_type(4))) float f32x4;
typedef unsigned short u16t;

#define MFMA16(a, b, c) __builtin_amdgcn_mfma_f32_16x16x32_bf16((a), (b), (c), 0, 0, 0)
#define GLDS16(gp, lp)                                                        \
  __builtin_amdgcn_global_load_lds(                                           \
      (__attribute__((address_space(1))) void*)(gp),                          \
      (__attribute__((address_space(3))) void*)(lp), 16, 0, 0)

static constexpr float L2E = 1.44269504f;   // log2(e)
static constexpr float MASKV = -1.0e30f;    // finite mask sentinel (no inf paths)
static constexpr float MASKTH = -5.0e29f;   // "is real score" threshold
static constexpr int PSTR = 72; // >= 64 keys/row; 144 B: b128-aligned, de-pow2

__device__ __forceinline__ u16t f2b(float f) {
  unsigned u = __builtin_bit_cast(unsigned, f);
  u = u + 0x7fffu + ((u >> 16) & 1u); // RNE
  return (u16t)(u >> 16);
}

// ---------------------------------------------------------------------------
// fp32 -> bf16 conversion of x and the 4 weight matrices, one fused launch.
// ---------------------------------------------------------------------------
__global__ void cvt5(const float* __restrict__ x, const float* __restrict__ wq,
                     const float* __restrict__ wk, const float* __restrict__ wv,
                     const float* __restrict__ wo, u16t* __restrict__ xb,
                     u16t* __restrict__ wqb, u16t* __restrict__ wkb,
                     u16t* __restrict__ wvb, u16t* __restrict__ wob) {
  const int bid = blockIdx.x;
  const float* src; u16t* dst; int gb;
  if (bid < 4096)      { src = x;  dst = xb;  gb = bid; }
  else if (bid < 4608) { src = wq; dst = wqb; gb = bid - 4096; }
  else if (bid < 5120) { src = wk; dst = wkb; gb = bid - 4608; }
  else if (bid < 5632) { src = wv; dst = wvb; gb = bid - 5120; }
  else                 { src = wo; dst = wob; gb = bid - 5632; }
  const size_t i = (size_t)gb * 256 + threadIdx.x; // 8-elem group index
  const float4 a = ((const float4*)src)[2 * i];
  const float4 b = ((const float4*)src)[2 * i + 1];
  u16x8 r;
  r[0] = f2b(a.x); r[1] = f2b(a.y); r[2] = f2b(a.z); r[3] = f2b(a.w);
  r[4] = f2b(b.x); r[5] = f2b(b.y); r[6] = f2b(b.z); r[7] = f2b(b.w);
  *(u16x8*)&dst[8 * i] = r;
}

// ---------------------------------------------------------------------------
// QKV GEMM. Q,K written [B,H,S,HD]; V written TRANSPOSED [B,H,HD,S].
// V^T epilogue vectorized (r runs along s -> u16x4 stores).
// ---------------------------------------------------------------------------
__global__ void gemm_qkv(const u16t* __restrict__ X,
                         const u16t* __restrict__ Wq, const u16t* __restrict__ Wk,
                         const u16t* __restrict__ Wv,
                         const float* __restrict__ bq, const float* __restrict__ bk,
                         const float* __restrict__ bv,
                         u16t* __restrict__ Qo, u16t* __restrict__ Ko,
                         u16t* __restrict__ Vo) {
  __shared__ __align__(16) u16t As[128 * 32];
  __shared__ __align__(16) u16t Bs[128 * 32];
  const int t = threadIdx.x, lane = t & 63, w = t >> 6;
  const int wr = w >> 1, wc = w & 1, m = lane & 15, quad = lane >> 4;
  const int rowBase = blockIdx.y * 128, colBase = blockIdx.x * 128;
  const int z = blockIdx.z;
  const u16t* W = (z == 0) ? Wq : ((z == 1) ? Wk : Wv);
  const float* bias = (z == 0) ? bq : ((z == 1) ? bk : bv);
  u16t* Out = (z == 0) ? Qo : ((z == 1) ? Ko : Vo);

  f32x4 acc[4][4];
#pragma unroll
  for (int i = 0; i < 4; i++)
#pragma unroll
    for (int j = 0; j < 4; j++) acc[i][j] = (f32x4){0.f, 0.f, 0.f, 0.f};

  const int lr = lane >> 2, lc = (lane & 3) * 8;
  for (int kt = 0; kt < 32; ++kt) {
#pragma unroll
    for (int i = 0; i < 2; ++i) {
      const int r0 = i * 64 + w * 16; // wave-uniform LDS region base
      GLDS16(&X[(size_t)(rowBase + r0 + lr) * 1024 + kt * 32 + lc], &As[r0 * 32]);
      GLDS16(&W[(size_t)(colBase + r0 + lr) * 1024 + kt * 32 + lc], &Bs[r0 * 32]);
    }
    __syncthreads();
    bf16x8 af[4], bfr[4];
#pragma unroll
    for (int i = 0; i < 4; i++)
      af[i] = *(const bf16x8*)&As[(wr * 64 + i * 16 + m) * 32 + quad * 8];
#pragma unroll
    for (int j = 0; j < 4; j++)
      bfr[j] = *(const bf16x8*)&Bs[(wc * 64 + j * 16 + m) * 32 + quad * 8];
#pragma unroll
    for (int i = 0; i < 4; i++)
#pragma unroll
      for (int j = 0; j < 4; j++) acc[i][j] = MFMA16(af[i], bfr[j], acc[i][j]);
    __syncthreads();
  }

  if (z == 2) {
    // V^T epilogue: row s runs along r -> vectorized 4x bf16 store
#pragma unroll
    for (int j = 0; j < 4; j++) {
      const int col = colBase + wc * 64 + j * 16 + m;
      const float bv_ = bias[col];
      const int h = col >> 6, hd = col & 63;
#pragma unroll
      for (int i = 0; i < 4; i++) {
        const int row0 = rowBase + wr * 64 + i * 16 + quad * 4;
        const int b_ = row0 >> 10, s0 = row0 & 1023;
        u16x4 ov;
#pragma unroll
        for (int r = 0; r < 4; r++) ov[r] = f2b(acc[i][j][r] + bv_);
        *(u16x4*)&Out[(((size_t)b_ * 16 + h) * 64 + hd) * 1024 + s0] = ov;
      }
    }
  } else {
#pragma unroll
    for (int j = 0; j < 4; j++) {
      const int col = colBase + wc * 64 + j * 16 + m;
      const float bv_ = bias[col];
      const int h = col >> 6, hd = col & 63;
#pragma unroll
      for (int i = 0; i < 4; i++) {
#pragma unroll
        for (int r = 0; r < 4; r++) {
          const int row = rowBase + wr * 64 + i * 16 + quad * 4 + r;
          const int b_ = row >> 10, s_ = row & 1023;
          Out[(((size_t)b_ * 16 + h) * 1024 + s_) * 64 + hd] = f2b(acc[i][j][r] + bv_);
        }
      }
    }
  }
}

// ---------------------------------------------------------------------------
// Output GEMM, operand-SWAPPED MFMA: C-layout becomes lane&15 -> out-row,
// quad*4+r -> out-col  ==> contiguous float4 stores (fp32 out).
// ---------------------------------------------------------------------------
__global__ void gemm_o(const u16t* __restrict__ A, const u16t* __restrict__ W,
                       const float* __restrict__ bias, float* __restrict__ Out) {
  __shared__ __align__(16) u16t As[128 * 32];
  __shared__ __align__(16) u16t Bs[128 * 32];
  const int t = threadIdx.x, lane = t & 63, w = t >> 6;
  const int wr = w >> 1, wc = w & 1, m = lane & 15, quad = lane >> 4;
  const int rowBase = blockIdx.y * 128, colBase = blockIdx.x * 128;

  f32x4 acc[4][4];
#pragma unroll
  for (int i = 0; i < 4; i++)
#pragma unroll
    for (int j = 0; j < 4; j++) acc[i][j] = (f32x4){0.f, 0.f, 0.f, 0.f};

  const int lr = lane >> 2, lc = (lane & 3) * 8;
  for (int kt = 0; kt < 32; ++kt) {
#pragma unroll
    for (int i = 0; i < 2; ++i) {
      const int r0 = i * 64 + w * 16;
      GLDS16(&A[(size_t)(rowBase + r0 + lr) * 1024 + kt * 32 + lc], &As[r0 * 32]);
      GLDS16(&W[(size_t)(colBase + r0 + lr) * 1024 + kt * 32 + lc], &Bs[r0 * 32]);
    }
    __syncthreads();
    bf16x8 af[4], bfr[4];
#pragma unroll
    for (int i = 0; i < 4; i++)
      af[i] = *(const bf16x8*)&As[(wr * 64 + i * 16 + m) * 32 + quad * 8];
#pragma unroll
    for (int j = 0; j < 4; j++)
      bfr[j] = *(const bf16x8*)&Bs[(wc * 64 + j * 16 + m) * 32 + quad * 8];
#pragma unroll
    for (int i = 0; i < 4; i++)
#pragma unroll
      for (int j = 0; j < 4; j++)
        acc[i][j] = MFMA16(bfr[j], af[i], acc[i][j]); // SWAPPED
    __syncthreads();
  }

#pragma unroll
  for (int i = 0; i < 4; i++) {
    const int row = rowBase + wr * 64 + i * 16 + m;
#pragma unroll
    for (int j = 0; j < 4; j++) {
      const int col0 = colBase + wc * 64 + j * 16 + quad * 4;
      const float4 b4 = *(const float4*)&bias[col0];
      float4 ov;
      ov.x = acc[i][j][0] + b4.x;
      ov.y = acc[i][j][1] + b4.y;
      ov.z = acc[i][j][2] + b4.z;
      ov.w = acc[i][j][3] + b4.w;
      *(float4*)&Out[(size_t)row * 1024 + col0] = ov;
    }
  }
}

// ---------------------------------------------------------------------------
// Flash attention v4: paired q-tiles + shared K/V + software-pipelined loads.
// __launch_bounds__(256,4): VGPR cap 128 (grid supplies 4 waves/SIMD) so the
// scheduler can hold a full iteration's K/V loads in flight. K(kt+1) is
// prefetched into the dead kf regs after both score phases; V(kt) issues
// before the softmax chains. Causal select only on diagonal k-tiles.
// ---------------------------------------------------------------------------
template <bool DIAG>
__device__ __forceinline__ void score_tile(const bf16x8* kf, bf16x8 qf0,
                                           bf16x8 qf1, int kb, int qq, int quad,
                                           const float* maskS, f32x4* sc,
                                           float& rmax) {
#pragma unroll
  for (int nt = 0; nt < 4; nt++) {
    f32x4 c = (f32x4){0.f, 0.f, 0.f, 0.f};
    c = MFMA16(kf[2 * nt], qf0, c);
    c = MFMA16(kf[2 * nt + 1], qf1, c);
    const int kt16 = kb + nt * 16;
    const float4 madd = *(const float4*)&maskS[kt16 + quad * 4];
    const float ma[4] = {madd.x, madd.y, madd.z, madd.w};
    const int kq = qq - kt16 - quad * 4; // causal: r <= kq
#pragma unroll
    for (int r = 0; r < 4; r++) {
      float s = c[r] * 0.125f + ma[r];
      if (DIAG) s = (r <= kq) ? s : MASKV;
      sc[nt][r] = s;
      rmax = fmaxf(rmax, s);
    }
  }
}

__device__ __forceinline__ float softmax_update(const f32x4* sc, float rmax,
                                                float& mi, float& li,
                                                u16t* Prow, int m, int quad) {
  rmax = fmaxf(rmax, __shfl_xor(rmax, 16));
  rmax = fmaxf(rmax, __shfl_xor(rmax, 32));
  const float mn = fmaxf(mi, rmax);
  const float alpha = exp2f((mi - mn) * L2E); // finite arg; underflows to 0
  mi = mn;
  float rsum = 0.f;
#pragma unroll
  for (int nt = 0; nt < 4; nt++) {
    float p[4];
#pragma unroll
    for (int r = 0; r < 4; r++) {
      p[r] = (sc[nt][r] > MASKTH) ? exp2f((sc[nt][r] - mn) * L2E) : 0.f;
      rsum += p[r];
    }
#if __has_builtin(__builtin_amdgcn_cvt_pk_bf16_f32)
    uint2 pk;
    pk.x = __builtin_bit_cast(unsigned, __builtin_amdgcn_cvt_pk_bf16_f32(p[0], p[1]));
    pk.y = __builtin_bit_cast(unsigned, __builtin_amdgcn_cvt_pk_bf16_f32(p[2], p[3]));
    *(uint2*)&Prow[m * PSTR + nt * 16 + quad * 4] = pk;
#else
    u16x4 pw;
#pragma unroll
    for (int r = 0; r < 4; r++) pw[r] = f2b(p[r]);
    *(u16x4*)&Prow[m * PSTR + nt * 16 + quad * 4] = pw;
#endif
  }
  rsum += __shfl_xor(rsum, 16);
  rsum += __shfl_xor(rsum, 32);
  li = li * alpha + rsum;
  return alpha;
}

__global__ __launch_bounds__(256, 4) void attn(const u16t* __restrict__ Q,
                                               const u16t* __restrict__ K,
                                               const u16t* __restrict__ VT,
                                               const int* __restrict__ ids,
                                               u16t* __restrict__ Oo) {
  __shared__ __align__(16) float maskS[1024];
  __shared__ __align__(16) u16t Ps[4][2][16 * PSTR];
  const int t = threadIdx.x, lane = t & 63, w = t >> 6;
  const int m = lane & 15, quad = lane >> 4;
  const int h = blockIdx.x, p = blockIdx.y, b = blockIdx.z;
  const int qtA = p, qtB = 15 - p;
  const size_t hoff = ((size_t)b * 16 + h) * 1024 * 64;
  const int qbaseA = qtA * 64 + w * 16, qbaseB = qtB * 64 + w * 16;
  const int qA = qbaseA + m, qB = qbaseB + m;

  // pad-mask -> LDS (additive: 0 or -1e30), once per block
  {
    const int4 iv = *(const int4*)&ids[b * 1024 + t * 4];
    float4 mv;
    mv.x = (iv.x == 1) ? MASKV : 0.f;
    mv.y = (iv.y == 1) ? MASKV : 0.f;
    mv.z = (iv.z == 1) ? MASKV : 0.f;
    mv.w = (iv.w == 1) ? MASKV : 0.f;
    *(float4*)&maskS[t * 4] = mv;
  }
  __syncthreads();

  // Q fragments (B-operand): lane m holds Q[q][quad*8..+7]
  const bf16x8 qfA0 = *(const bf16x8*)&Q[hoff + (size_t)qA * 64 + quad * 8];
  const bf16x8 qfA1 = *(const bf16x8*)&Q[hoff + (size_t)qA * 64 + 32 + quad * 8];
  const bf16x8 qfB0 = *(const bf16x8*)&Q[hoff + (size_t)qB * 64 + quad * 8];
  const bf16x8 qfB1 = *(const bf16x8*)&Q[hoff + (size_t)qB * 64 + 32 + quad * 8];

  float miA = MASKV, liA = 0.f, miB = MASKV, liB = 0.f;
  f32x4 oA[4], oB[4];
#pragma unroll
  for (int ot = 0; ot < 4; ot++) {
    oA[ot] = (f32x4){0.f, 0.f, 0.f, 0.f};
    oB[ot] = (f32x4){0.f, 0.f, 0.f, 0.f};
  }

  // preload K fragments for kt=0
  bf16x8 kf[8];
#pragma unroll
  for (int nt = 0; nt < 4; nt++) {
    const int key = nt * 16 + m;
    kf[2 * nt]     = *(const bf16x8*)&K[hoff + (size_t)key * 64 + quad * 8];
    kf[2 * nt + 1] = *(const bf16x8*)&K[hoff + (size_t)key * 64 + 32 + quad * 8];
  }

  for (int kt = 0; kt <= qtB; ++kt) {
    const int kb = kt * 64;
    const bool joint = (kt <= qtA);

    // ---- scores (consume kf) ----
    f32x4 scB[4], scA[4];
    float rmB = MASKV, rmA = MASKV;
    if (kt == qtB) score_tile<true>(kf, qfB0, qfB1, kb, qB, quad, maskS, scB, rmB);
    else           score_tile<false>(kf, qfB0, qfB1, kb, qB, quad, maskS, scB, rmB);
    if (joint) {
      if (kt == qtA) score_tile<true>(kf, qfA0, qfA1, kb, qA, quad, maskS, scA, rmA);
      else           score_tile<false>(kf, qfA0, qfA1, kb, qA, quad, maskS, scA, rmA);
    }

    // ---- prefetch K(kt+1) into kf (regs dead after scores) ----
    const int kbn = (kt < qtB) ? kb + 64 : 0;
#pragma unroll
    for (int nt = 0; nt < 4; nt++) {
      const int key = kbn + nt * 16 + m;
      kf[2 * nt]     = *(const bf16x8*)&K[hoff + (size_t)key * 64 + quad * 8];
      kf[2 * nt + 1] = *(const bf16x8*)&K[hoff + (size_t)key * 64 + 32 + quad * 8];
    }

    // ---- V fragments for current iter (used at the end) ----
    bf16x8 vf[8];
#pragma unroll
    for (int ot = 0; ot < 4; ot++) {
      const int hd = ot * 16 + m;
      vf[2 * ot]     = *(const bf16x8*)&VT[hoff + (size_t)hd * 1024 + kb + quad * 8];
      vf[2 * ot + 1] = *(const bf16x8*)&VT[hoff + (size_t)hd * 1024 + kb + 32 + quad * 8];
    }

    // ---- softmax (serial VALU; overlaps the loads above) ----
    const float aB = softmax_update(scB, rmB, miB, liB, Ps[w][1], m, quad);
    float aA = 1.f;
    if (joint) aA = softmax_update(scA, rmA, miA, liA, Ps[w][0], m, quad);

    // ---- PV for B ----
#pragma unroll
    for (int ot = 0; ot < 4; ot++)
#pragma unroll
      for (int r = 0; r < 4; r++) oB[ot][r] *= aB;
    {
      const bf16x8 p0 = *(const bf16x8*)&Ps[w][1][m * PSTR + quad * 8];
      const bf16x8 p1 = *(const bf16x8*)&Ps[w][1][m * PSTR + 32 + quad * 8];
#pragma unroll
      for (int ot = 0; ot < 4; ot++) {
        oB[ot] = MFMA16(vf[2 * ot], p0, oB[ot]);
        oB[ot] = MFMA16(vf[2 * ot + 1], p1, oB[ot]);
      }
    }
    // ---- PV for A (joint only) ----
    if (joint) {
#pragma unroll
      for (int ot = 0; ot < 4; ot++)
#pragma unroll
        for (int r = 0; r < 4; r++) oA[ot][r] *= aA;
      const bf16x8 p0 = *(const bf16x8*)&Ps[w][0][m * PSTR + quad * 8];
      const bf16x8 p1 = *(const bf16x8*)&Ps[w][0][m * PSTR + 32 + quad * 8];
#pragma unroll
      for (int ot = 0; ot < 4; ot++) {
        oA[ot] = MFMA16(vf[2 * ot], p0, oA[ot]);
        oA[ot] = MFMA16(vf[2 * ot + 1], p1, oA[ot]);
      }
    }
  }

  // epilogue: lane owns q-row; cols h*64 + ot*16 + quad*4 + r (4 contiguous)
  const float invA = liA > 1e-30f ? 1.f / liA : 0.f;
  const float invB = liB > 1e-30f ? 1.f / liB : 0.f;
#pragma unroll
  for (int ot = 0; ot < 4; ot++) {
    u16x4 owA, owB;
#pragma unroll
    for (int r = 0; r < 4; r++) {
      owA[r] = f2b(oA[ot][r] * invA);
      owB[r] = f2b(oB[ot][r] * invB);
    }
    const int colb = h * 64 + ot * 16 + quad * 4;
    *(u16x4*)&Oo[((size_t)(b * 1024 + qA)) * 1024 + colb] = owA;
    *(u16x4*)&Oo[((size_t)(b * 1024 + qB)) * 1024 + colb] = owB;
  }
}

// ---------------------------------------------------------------------------
extern "C" void kernel_launch(void* const* d_in, const int* in_sizes, int n_in,
                              void* d_out, int out_size, void* d_ws, size_t ws_size,
                              hipStream_t stream) {
  const float* x  = (const float*)d_in[0];
  const int*   ids = (const int*)d_in[1];
  const float* Wq = (const float*)d_in[2];
  const float* bq = (const float*)d_in[3];
  const float* Wk = (const float*)d_in[4];
  const float* bk = (const float*)d_in[5];
  const float* Wv = (const float*)d_in[6];
  const float* bv = (const float*)d_in[7];
  const float* Wo = (const float*)d_in[8];
  const float* bo = (const float*)d_in[9];
  float* out = (float*)d_out;

  // ws layout (bf16 elems): XB 8.4M | WqB,WkB,WvB,WoB 1M each | Q,K,V^T 8.4M
  u16t* XB  = (u16t*)d_ws;
  u16t* WqB = XB  + 8388608;
  u16t* WkB = WqB + 1048576;
  u16t* WvB = WkB + 1048576;
  u16t* WoB = WvB + 1048576;
  u16t* Qw  = WoB + 1048576;
  u16t* Kw  = Qw  + 8388608;
  u16t* Vw  = Kw  + 8388608; // holds V^T [B,H,HD,S]
  u16t* AO  = XB; // reuse after gemm_qkv consumed XB

  cvt5<<<6144, 256, 0, stream>>>(x, Wq, Wk, Wv, Wo, XB, WqB, WkB, WvB, WoB);
  gemm_qkv<<<dim3(8, 64, 3), 256, 0, stream>>>(XB, WqB, WkB, WvB, bq, bk, bv,
                                               Qw, Kw, Vw);
  attn<<<dim3(16, 8, 8), 256, 0, stream>>>(Qw, Kw, Vw, ids, AO);
  gemm_o<<<dim3(8, 64, 1), 256, 0, stream>>>(AO, WoB, bo, out);
}

// Round 10
// 390.568 us; speedup vs baseline: 1.1697x; 1.0055x over previous
//
#include <hip/hip_runtime.h>

typedef __attribute__((ext_vector_type(8))) short bf16x8;
typedef __attribute__((ext_vector_type(8))) unsigned short u16x8;
typedef __attribute__((ext_vector_type(4))) unsigned short u16x4;
typedef __attribute__((ext_vector_type(4))) float f32x4;
typedef unsigned short u16t;

#define MFMA16(a, b, c) __builtin_amdgcn_mfma_f32_16x16x32_bf16((a), (b), (c), 0, 0, 0)
#define GLDS16(gp, lp)                                                        \
  __builtin_amdgcn_global_load_lds(                                           \
      (__attribute__((address_space(1))) void*)(gp),                          \
      (__attribute__((address_space(3))) void*)(lp), 16, 0, 0)

static constexpr float L2E = 1.44269504f;   // log2(e)
static constexpr float MASKV = -1.0e30f;    // finite mask sentinel (no inf paths)
static constexpr float MASKTH = -5.0e29f;   // "is real score" threshold
static constexpr int PSTR = 72; // >= 64 keys/row; 144 B: b128-aligned, de-pow2

__device__ __forceinline__ u16t f2b(float f) {
  unsigned u = __builtin_bit_cast(unsigned, f);
  u = u + 0x7fffu + ((u >> 16) & 1u); // RNE
  return (u16t)(u >> 16);
}

// ---------------------------------------------------------------------------
// fp32 -> bf16 conversion of x and the 4 weight matrices, one fused launch.
// ---------------------------------------------------------------------------
__global__ void cvt5(const float* __restrict__ x, const float* __restrict__ wq,
                     const float* __restrict__ wk, const float* __restrict__ wv,
                     const float* __restrict__ wo, u16t* __restrict__ xb,
                     u16t* __restrict__ wqb, u16t* __restrict__ wkb,
                     u16t* __restrict__ wvb, u16t* __restrict__ wob) {
  const int bid = blockIdx.x;
  const float* src; u16t* dst; int gb;
  if (bid < 4096)      { src = x;  dst = xb;  gb = bid; }
  else if (bid < 4608) { src = wq; dst = wqb; gb = bid - 4096; }
  else if (bid < 5120) { src = wk; dst = wkb; gb = bid - 4608; }
  else if (bid < 5632) { src = wv; dst = wvb; gb = bid - 5120; }
  else                 { src = wo; dst = wob; gb = bid - 5632; }
  const size_t i = (size_t)gb * 256 + threadIdx.x; // 8-elem group index
  const float4 a = ((const float4*)src)[2 * i];
  const float4 b = ((const float4*)src)[2 * i + 1];
  u16x8 r;
  r[0] = f2b(a.x); r[1] = f2b(a.y); r[2] = f2b(a.z); r[3] = f2b(a.w);
  r[4] = f2b(b.x); r[5] = f2b(b.y); r[6] = f2b(b.z); r[7] = f2b(b.w);
  *(u16x8*)&dst[8 * i] = r;
}

// ---------------------------------------------------------------------------
// QKV GEMM. Q,K written [B,H,S,HD]; V written TRANSPOSED [B,H,HD,S].
// ---------------------------------------------------------------------------
__global__ void gemm_qkv(const u16t* __restrict__ X,
                         const u16t* __restrict__ Wq, const u16t* __restrict__ Wk,
                         const u16t* __restrict__ Wv,
                         const float* __restrict__ bq, const float* __restrict__ bk,
                         const float* __restrict__ bv,
                         u16t* __restrict__ Qo, u16t* __restrict__ Ko,
                         u16t* __restrict__ Vo) {
  __shared__ __align__(16) u16t As[128 * 32];
  __shared__ __align__(16) u16t Bs[128 * 32];
  const int t = threadIdx.x, lane = t & 63, w = t >> 6;
  const int wr = w >> 1, wc = w & 1, m = lane & 15, quad = lane >> 4;
  const int rowBase = blockIdx.y * 128, colBase = blockIdx.x * 128;
  const int z = blockIdx.z;
  const u16t* W = (z == 0) ? Wq : ((z == 1) ? Wk : Wv);
  const float* bias = (z == 0) ? bq : ((z == 1) ? bk : bv);
  u16t* Out = (z == 0) ? Qo : ((z == 1) ? Ko : Vo);

  f32x4 acc[4][4];
#pragma unroll
  for (int i = 0; i < 4; i++)
#pragma unroll
    for (int j = 0; j < 4; j++) acc[i][j] = (f32x4){0.f, 0.f, 0.f, 0.f};

  const int lr = lane >> 2, lc = (lane & 3) * 8;
  for (int kt = 0; kt < 32; ++kt) {
#pragma unroll
    for (int i = 0; i < 2; ++i) {
      const int r0 = i * 64 + w * 16; // wave-uniform LDS region base
      GLDS16(&X[(size_t)(rowBase + r0 + lr) * 1024 + kt * 32 + lc], &As[r0 * 32]);
      GLDS16(&W[(size_t)(colBase + r0 + lr) * 1024 + kt * 32 + lc], &Bs[r0 * 32]);
    }
    __syncthreads();
    bf16x8 af[4], bfr[4];
#pragma unroll
    for (int i = 0; i < 4; i++)
      af[i] = *(const bf16x8*)&As[(wr * 64 + i * 16 + m) * 32 + quad * 8];
#pragma unroll
    for (int j = 0; j < 4; j++)
      bfr[j] = *(const bf16x8*)&Bs[(wc * 64 + j * 16 + m) * 32 + quad * 8];
#pragma unroll
    for (int i = 0; i < 4; i++)
#pragma unroll
      for (int j = 0; j < 4; j++) acc[i][j] = MFMA16(af[i], bfr[j], acc[i][j]);
    __syncthreads();
  }

  if (z == 2) {
    // V^T epilogue: row s runs along r -> vectorized 4x bf16 store
#pragma unroll
    for (int j = 0; j < 4; j++) {
      const int col = colBase + wc * 64 + j * 16 + m;
      const float bv_ = bias[col];
      const int h = col >> 6, hd = col & 63;
#pragma unroll
      for (int i = 0; i < 4; i++) {
        const int row0 = rowBase + wr * 64 + i * 16 + quad * 4;
        const int b_ = row0 >> 10, s0 = row0 & 1023;
        u16x4 ov;
#pragma unroll
        for (int r = 0; r < 4; r++) ov[r] = f2b(acc[i][j][r] + bv_);
        *(u16x4*)&Out[(((size_t)b_ * 16 + h) * 64 + hd) * 1024 + s0] = ov;
      }
    }
  } else {
#pragma unroll
    for (int j = 0; j < 4; j++) {
      const int col = colBase + wc * 64 + j * 16 + m;
      const float bv_ = bias[col];
      const int h = col >> 6, hd = col & 63;
#pragma unroll
      for (int i = 0; i < 4; i++) {
#pragma unroll
        for (int r = 0; r < 4; r++) {
          const int row = rowBase + wr * 64 + i * 16 + quad * 4 + r;
          const int b_ = row >> 10, s_ = row & 1023;
          Out[(((size_t)b_ * 16 + h) * 1024 + s_) * 64 + hd] = f2b(acc[i][j][r] + bv_);
        }
      }
    }
  }
}

// ---------------------------------------------------------------------------
// Output GEMM, operand-SWAPPED MFMA: C-layout becomes lane&15 -> out-row,
// quad*4+r -> out-col  ==> contiguous float4 stores (fp32 out).
// ---------------------------------------------------------------------------
__global__ void gemm_o(const u16t* __restrict__ A, const u16t* __restrict__ W,
                       const float* __restrict__ bias, float* __restrict__ Out) {
  __shared__ __align__(16) u16t As[128 * 32];
  __shared__ __align__(16) u16t Bs[128 * 32];
  const int t = threadIdx.x, lane = t & 63, w = t >> 6;
  const int wr = w >> 1, wc = w & 1, m = lane & 15, quad = lane >> 4;
  const int rowBase = blockIdx.y * 128, colBase = blockIdx.x * 128;

  f32x4 acc[4][4];
#pragma unroll
  for (int i = 0; i < 4; i++)
#pragma unroll
    for (int j = 0; j < 4; j++) acc[i][j] = (f32x4){0.f, 0.f, 0.f, 0.f};

  const int lr = lane >> 2, lc = (lane & 3) * 8;
  for (int kt = 0; kt < 32; ++kt) {
#pragma unroll
    for (int i = 0; i < 2; ++i) {
      const int r0 = i * 64 + w * 16;
      GLDS16(&A[(size_t)(rowBase + r0 + lr) * 1024 + kt * 32 + lc], &As[r0 * 32]);
      GLDS16(&W[(size_t)(colBase + r0 + lr) * 1024 + kt * 32 + lc], &Bs[r0 * 32]);
    }
    __syncthreads();
    bf16x8 af[4], bfr[4];
#pragma unroll
    for (int i = 0; i < 4; i++)
      af[i] = *(const bf16x8*)&As[(wr * 64 + i * 16 + m) * 32 + quad * 8];
#pragma unroll
    for (int j = 0; j < 4; j++)
      bfr[j] = *(const bf16x8*)&Bs[(wc * 64 + j * 16 + m) * 32 + quad * 8];
#pragma unroll
    for (int i = 0; i < 4; i++)
#pragma unroll
      for (int j = 0; j < 4; j++)
        acc[i][j] = MFMA16(bfr[j], af[i], acc[i][j]); // SWAPPED
    __syncthreads();
  }

#pragma unroll
  for (int i = 0; i < 4; i++) {
    const int row = rowBase + wr * 64 + i * 16 + m;
#pragma unroll
    for (int j = 0; j < 4; j++) {
      const int col0 = colBase + wc * 64 + j * 16 + quad * 4;
      const float4 b4 = *(const float4*)&bias[col0];
      float4 ov;
      ov.x = acc[i][j][0] + b4.x;
      ov.y = acc[i][j][1] + b4.y;
      ov.z = acc[i][j][2] + b4.z;
      ov.w = acc[i][j][3] + b4.w;
      *(float4*)&Out[(size_t)row * 1024 + col0] = ov;
    }
  }
}

// ---------------------------------------------------------------------------
// Flash attention v5 = v4 structure + amdgpu_waves_per_eu(4,4): pin exactly
// 4 waves/EU (matches the 4-blocks/CU grid) so the allocator gets the full
// 128-VGPR budget -> kf/vf prefetch arrays live in registers, no scratch
// spills (round-9: VGPR stuck at 64, 283 MB spill writes).
// ---------------------------------------------------------------------------
template <bool DIAG>
__device__ __forceinline__ void score_tile(const bf16x8* kf, bf16x8 qf0,
                                           bf16x8 qf1, int kb, int qq, int quad,
                                           const float* maskS, f32x4* sc,
                                           float& rmax) {
#pragma unroll
  for (int nt = 0; nt < 4; nt++) {
    f32x4 c = (f32x4){0.f, 0.f, 0.f, 0.f};
    c = MFMA16(kf[2 * nt], qf0, c);
    c = MFMA16(kf[2 * nt + 1], qf1, c);
    const int kt16 = kb + nt * 16;
    const float4 madd = *(const float4*)&maskS[kt16 + quad * 4];
    const float ma[4] = {madd.x, madd.y, madd.z, madd.w};
    const int kq = qq - kt16 - quad * 4; // causal: r <= kq
#pragma unroll
    for (int r = 0; r < 4; r++) {
      float s = c[r] * 0.125f + ma[r];
      if (DIAG) s = (r <= kq) ? s : MASKV;
      sc[nt][r] = s;
      rmax = fmaxf(rmax, s);
    }
  }
}

__device__ __forceinline__ float softmax_update(const f32x4* sc, float rmax,
                                                float& mi, float& li,
                                                u16t* Prow, int m, int quad) {
  rmax = fmaxf(rmax, __shfl_xor(rmax, 16));
  rmax = fmaxf(rmax, __shfl_xor(rmax, 32));
  const float mn = fmaxf(mi, rmax);
  const float alpha = exp2f((mi - mn) * L2E); // finite arg; underflows to 0
  mi = mn;
  float rsum = 0.f;
#pragma unroll
  for (int nt = 0; nt < 4; nt++) {
    float p[4];
#pragma unroll
    for (int r = 0; r < 4; r++) {
      p[r] = (sc[nt][r] > MASKTH) ? exp2f((sc[nt][r] - mn) * L2E) : 0.f;
      rsum += p[r];
    }
#if __has_builtin(__builtin_amdgcn_cvt_pk_bf16_f32)
    uint2 pk;
    pk.x = __builtin_bit_cast(unsigned, __builtin_amdgcn_cvt_pk_bf16_f32(p[0], p[1]));
    pk.y = __builtin_bit_cast(unsigned, __builtin_amdgcn_cvt_pk_bf16_f32(p[2], p[3]));
    *(uint2*)&Prow[m * PSTR + nt * 16 + quad * 4] = pk;
#else
    u16x4 pw;
#pragma unroll
    for (int r = 0; r < 4; r++) pw[r] = f2b(p[r]);
    *(u16x4*)&Prow[m * PSTR + nt * 16 + quad * 4] = pw;
#endif
  }
  rsum += __shfl_xor(rsum, 16);
  rsum += __shfl_xor(rsum, 32);
  li = li * alpha + rsum;
  return alpha;
}

__global__ __launch_bounds__(256)
__attribute__((amdgpu_waves_per_eu(4, 4)))
void attn(const u16t* __restrict__ Q, const u16t* __restrict__ K,
          const u16t* __restrict__ VT, const int* __restrict__ ids,
          u16t* __restrict__ Oo) {
  __shared__ __align__(16) float maskS[1024];
  __shared__ __align__(16) u16t Ps[4][2][16 * PSTR];
  const int t = threadIdx.x, lane = t & 63, w = t >> 6;
  const int m = lane & 15, quad = lane >> 4;
  const int h = blockIdx.x, p = blockIdx.y, b = blockIdx.z;
  const int qtA = p, qtB = 15 - p;
  const size_t hoff = ((size_t)b * 16 + h) * 1024 * 64;
  const int qbaseA = qtA * 64 + w * 16, qbaseB = qtB * 64 + w * 16;
  const int qA = qbaseA + m, qB = qbaseB + m;

  // pad-mask -> LDS (additive: 0 or -1e30), once per block
  {
    const int4 iv = *(const int4*)&ids[b * 1024 + t * 4];
    float4 mv;
    mv.x = (iv.x == 1) ? MASKV : 0.f;
    mv.y = (iv.y == 1) ? MASKV : 0.f;
    mv.z = (iv.z == 1) ? MASKV : 0.f;
    mv.w = (iv.w == 1) ? MASKV : 0.f;
    *(float4*)&maskS[t * 4] = mv;
  }
  __syncthreads();

  // Q fragments (B-operand): lane m holds Q[q][quad*8..+7]
  const bf16x8 qfA0 = *(const bf16x8*)&Q[hoff + (size_t)qA * 64 + quad * 8];
  const bf16x8 qfA1 = *(const bf16x8*)&Q[hoff + (size_t)qA * 64 + 32 + quad * 8];
  const bf16x8 qfB0 = *(const bf16x8*)&Q[hoff + (size_t)qB * 64 + quad * 8];
  const bf16x8 qfB1 = *(const bf16x8*)&Q[hoff + (size_t)qB * 64 + 32 + quad * 8];

  float miA = MASKV, liA = 0.f, miB = MASKV, liB = 0.f;
  f32x4 oA[4], oB[4];
#pragma unroll
  for (int ot = 0; ot < 4; ot++) {
    oA[ot] = (f32x4){0.f, 0.f, 0.f, 0.f};
    oB[ot] = (f32x4){0.f, 0.f, 0.f, 0.f};
  }

  // preload K fragments for kt=0
  bf16x8 kf[8];
#pragma unroll
  for (int nt = 0; nt < 4; nt++) {
    const int key = nt * 16 + m;
    kf[2 * nt]     = *(const bf16x8*)&K[hoff + (size_t)key * 64 + quad * 8];
    kf[2 * nt + 1] = *(const bf16x8*)&K[hoff + (size_t)key * 64 + 32 + quad * 8];
  }

  for (int kt = 0; kt <= qtB; ++kt) {
    const int kb = kt * 64;
    const bool joint = (kt <= qtA);

    // ---- scores (consume kf) ----
    f32x4 scB[4], scA[4];
    float rmB = MASKV, rmA = MASKV;
    if (kt == qtB) score_tile<true>(kf, qfB0, qfB1, kb, qB, quad, maskS, scB, rmB);
    else           score_tile<false>(kf, qfB0, qfB1, kb, qB, quad, maskS, scB, rmB);
    if (joint) {
      if (kt == qtA) score_tile<true>(kf, qfA0, qfA1, kb, qA, quad, maskS, scA, rmA);
      else           score_tile<false>(kf, qfA0, qfA1, kb, qA, quad, maskS, scA, rmA);
    }

    // ---- prefetch K(kt+1) into kf (regs dead after scores) ----
    const int kbn = (kt < qtB) ? kb + 64 : 0;
#pragma unroll
    for (int nt = 0; nt < 4; nt++) {
      const int key = kbn + nt * 16 + m;
      kf[2 * nt]     = *(const bf16x8*)&K[hoff + (size_t)key * 64 + quad * 8];
      kf[2 * nt + 1] = *(const bf16x8*)&K[hoff + (size_t)key * 64 + 32 + quad * 8];
    }

    // ---- V fragments for current iter (used at the end) ----
    bf16x8 vf[8];
#pragma unroll
    for (int ot = 0; ot < 4; ot++) {
      const int hd = ot * 16 + m;
      vf[2 * ot]     = *(const bf16x8*)&VT[hoff + (size_t)hd * 1024 + kb + quad * 8];
      vf[2 * ot + 1] = *(const bf16x8*)&VT[hoff + (size_t)hd * 1024 + kb + 32 + quad * 8];
    }

    // ---- softmax (serial VALU; overlaps the loads above) ----
    const float aB = softmax_update(scB, rmB, miB, liB, Ps[w][1], m, quad);
    float aA = 1.f;
    if (joint) aA = softmax_update(scA, rmA, miA, liA, Ps[w][0], m, quad);

    // ---- PV for B ----
#pragma unroll
    for (int ot = 0; ot < 4; ot++)
#pragma unroll
      for (int r = 0; r < 4; r++) oB[ot][r] *= aB;
    {
      const bf16x8 p0 = *(const bf16x8*)&Ps[w][1][m * PSTR + quad * 8];
      const bf16x8 p1 = *(const bf16x8*)&Ps[w][1][m * PSTR + 32 + quad * 8];
#pragma unroll
      for (int ot = 0; ot < 4; ot++) {
        oB[ot] = MFMA16(vf[2 * ot], p0, oB[ot]);
        oB[ot] = MFMA16(vf[2 * ot + 1], p1, oB[ot]);
      }
    }
    // ---- PV for A (joint only) ----
    if (joint) {
#pragma unroll
      for (int ot = 0; ot < 4; ot++)
#pragma unroll
        for (int r = 0; r < 4; r++) oA[ot][r] *= aA;
      const bf16x8 p0 = *(const bf16x8*)&Ps[w][0][m * PSTR + quad * 8];
      const bf16x8 p1 = *(const bf16x8*)&Ps[w][0][m * PSTR + 32 + quad * 8];
#pragma unroll
      for (int ot = 0; ot < 4; ot++) {
        oA[ot] = MFMA16(vf[2 * ot], p0, oA[ot]);
        oA[ot] = MFMA16(vf[2 * ot + 1], p1, oA[ot]);
      }
    }
  }

  // epilogue: lane owns q-row; cols h*64 + ot*16 + quad*4 + r (4 contiguous)
  const float invA = liA > 1e-30f ? 1.f / liA : 0.f;
  const float invB = liB > 1e-30f ? 1.f / liB : 0.f;
#pragma unroll
  for (int ot = 0; ot < 4; ot++) {
    u16x4 owA, owB;
#pragma unroll
    for (int r = 0; r < 4; r++) {
      owA[r] = f2b(oA[ot][r] * invA);
      owB[r] = f2b(oB[ot][r] * invB);
    }
    const int colb = h * 64 + ot * 16 + quad * 4;
    *(u16x4*)&Oo[((size_t)(b * 1024 + qA)) * 1024 + colb] = owA;
    *(u16x4*)&Oo[((size_t)(b * 1024 + qB)) * 1024 + colb] = owB;
  }
}

// ---------------------------------------------------------------------------
extern "C" void kernel_launch(void* const* d_in, const int* in_sizes, int n_in,
                              void* d_out, int out_size, void* d_ws, size_t ws_size,
                              hipStream_t stream) {
  const float* x  = (const float*)d_in[0];
  const int*   ids = (const int*)d_in[1];
  const float* Wq = (const float*)d_in[2];
  const float* bq = (const float*)d_in[3];
  const float* Wk = (const float*)d_in[4];
  const float* bk = (const float*)d_in[5];
  const float* Wv = (const float*)d_in[6];
  const float* bv = (const float*)d_in[7];
  const float* Wo = (const float*)d_in[8];
  const float* bo = (const float*)d_in[9];
  float* out = (float*)d_out;

  // ws layout (bf16 elems): XB 8.4M | WqB,WkB,WvB,WoB 1M each | Q,K,V^T 8.4M
  u16t* XB  = (u16t*)d_ws;
  u16t* WqB = XB  + 8388608;
  u16t* WkB = WqB + 1048576;
  u16t* WvB = WkB + 1048576;
  u16t* WoB = WvB + 1048576;
  u16t* Qw  = WoB + 1048576;
  u16t* Kw  = Qw  + 8388608;
  u16t* Vw  = Kw  + 8388608; // holds V^T [B,H,HD,S]
  u16t* AO  = XB; // reuse after gemm_qkv consumed XB

  cvt5<<<6144, 256, 0, stream>>>(x, Wq, Wk, Wv, Wo, XB, WqB, WkB, WvB, WoB);
  gemm_qkv<<<dim3(8, 64, 3), 256, 0, stream>>>(XB, WqB, WkB, WvB, bq, bk, bv,
                                               Qw, Kw, Vw);
  attn<<<dim3(16, 8, 8), 256, 0, stream>>>(Qw, Kw, Vw, ids, AO);
  gemm_o<<<dim3(8, 64, 1), 256, 0, stream>>>(AO, WoB, bo, out);
}